// Round 6
// baseline (349.387 us; speedup 1.0000x reference)
//
#include <hip/hip_runtime.h>
#include <math.h>

#define NN 512
#define NC 3
#define RING 16                 // ring-buffer rows; slot = row & 15
#define SLOTF (NC * NN)         // floats per ring slot (1536): [ch][512]
#define TBL   (RING * SLOTF)    // cu/cv table offset in floats (24576)

// Radial cutoff envelope e[i][j] = (r<4.5)/r, r=sqrt((i+1)^2+(j+1)^2), i,j in 0..3
__device__ __constant__ float d_env[16] = {
    0.70710678f, 0.44721360f, 0.31622777f, 0.24253563f,
    0.44721360f, 0.35355339f, 0.27735010f, 0.22360680f,
    0.31622777f, 0.27735010f, 0.23570226f, 0.00000000f,
    0.24253563f, 0.22360680f, 0.00000000f, 0.00000000f
};

// p-major sine table: ws[p*4 + j] = sin(pi * p * (j+1) / 511), p in 0..511.
__global__ __launch_bounds__(256) void sine_table_kernel(float* __restrict__ ws) {
    const int t = blockIdx.x * 256 + threadIdx.x;   // 2048 threads
    const int j = t & 3;
    const int p = t >> 2;
    ws[t] = sinf((float)M_PI * (float)p * (1.0f / 511.0f) * (float)(j + 1));
}

// Async global->LDS, 16 B per lane (dest must be linear: base + lane*16).
#define GLOAD_LDS(g, l)                                                        \
    __builtin_amdgcn_global_load_lds(                                          \
        (const __attribute__((address_space(1))) void*)(g),                    \
        (__attribute__((address_space(3))) void*)(l), 16, 0, 0)

// Persistent rolling-ring pipeline (round-5 post-mortem: kernel was
// latency-bound on the serial stage->vmcnt(0)->compute structure, not on the
// DS/VALU/HBM pipes). One 1024-thread block per CU; each owns a 128-row strip
// of one image and loops over 32 four-row groups. A 16-row LDS ring
// (slot = row & 15) is staged ahead with global_load_lds; the per-iteration
// s_waitcnt vmcnt(6) (NOT 0) keeps the next group's loads in flight across
// the barrier (T3/T4 counted-vmcnt pattern), so staging never drains the
// pipe, and each input row is fetched exactly once (no halo re-fetch).
// Slot-disjointness: writes go to rows = y0+5..y0+8 (mod 16), reads touch
// y0-1..y0+4 -- a 10-row span in a 16-ring, disjoint; one barrier/iter.
// LDS = 16*1536 + 128*8 floats = 102400 B -> 1 block/CU, grid 256 = 1/CU.
__global__ __launch_bounds__(1024) void diffeo_kernel(
    const float* __restrict__ xin,
    const float* __restrict__ Fx,
    const float* __restrict__ Fy,
    float* __restrict__ out,
    const float* __restrict__ ws,
    float scale)
{
    __shared__ float smem[TBL + 128 * 8];           // 102400 B

    const int tid = threadIdx.x;
    const int bid = blockIdx.x;
    // XCD-chunked bijective swizzle (256 % 8 == 0): XCD k gets 8 consecutive
    // images' strips.
    const int g  = ((bid & 7) << 5) | (bid >> 3);
    const int b  = g >> 2;                          // image
    const int ys = (g & 3) << 7;                    // strip start row (128-row strip)

    const float* __restrict__ base = xin + (size_t)b * NC * NN * NN;

    // ---- prologue: stage logical rows ys-1..ys+4 (6 rows x 3 ch = 2304 f4) ----
#pragma unroll
    for (int k = 0; k < 3; ++k) {
        const int f = tid + (k << 10);
        if (f < 2304) {
            const int rc = f >> 7;                  // 0..17: (ch,row) unit
            const int ch = (rc >= 12) ? 2 : ((rc >= 6) ? 1 : 0);
            const int ro = rc - ch * 6;
            const int lr = ys - 1 + ro;             // logical row (may be -1)
            const int sr = max(lr, 0);              // clamped source row
            GLOAD_LDS(base + ((ch << 18) | (sr << 9)) + ((f & 127) << 2),
                      smem + (lr & (RING - 1)) * SLOTF + ch * NN + ((f & 127) << 2));
        }
    }

    // ---- prologue: cu/cv for all 128 strip rows (1 value per thread) ----
    // cu[y][i] = scale * sum_j F[b,i,j]*env[i,j]*sy[y][j]; comp 0..3 = cu, 4..7 = cv
    {
        const int ri = tid >> 3, comp = tid & 7, i = comp & 3;
        const float* Fp = ((comp & 4) ? Fy : Fx) + b * 16 + i * 4;
        const float4 sy = *(const float4*)(ws + ((ys + ri) << 2));
        smem[TBL + (ri << 3) + comp] = scale *
            (Fp[0] * d_env[i * 4 + 0] * sy.x + Fp[1] * d_env[i * 4 + 1] * sy.y +
             Fp[2] * d_env[i * 4 + 2] * sy.z + Fp[3] * d_env[i * 4 + 3] * sy.w);
    }

    // Fixed per-thread x positions across all iterations -> sx in registers.
    const int xb   = tid & 255;
    const int wrow = tid >> 8;                      // 0..3 (wave-uniform)
    const float4 sxA = *(const float4*)(ws + (xb << 2));
    const float4 sxB = *(const float4*)(ws + ((xb + 256) << 2));

    float* __restrict__ ob = out + (size_t)b * NC * NN * NN;

    __syncthreads();    // prologue only: full vmcnt drain + barrier (once)

    for (int it = 0; it < 32; ++it) {
        const int y0 = ys + (it << 2);              // group rows y0..y0+3

        // ---- stage next group's new rows y0+5..y0+8 (1536 f4) ----
        if (it < 31) {
            {
                const int f  = tid;                 // rc 0..7 -> ch 0..1
                const int rc = f >> 7;
                const int ch = rc >> 2, ro = rc & 3;
                const int lr = y0 + 5 + ro;
                const int sr = min(lr, NN - 1);
                GLOAD_LDS(base + ((ch << 18) | (sr << 9)) + ((f & 127) << 2),
                          smem + (lr & (RING - 1)) * SLOTF + ch * NN + ((f & 127) << 2));
            }
            if (tid < 512) {                        // rc 8..11 -> ch 2
                const int f  = tid + 1024;
                const int ro = (f >> 7) & 3;
                const int lr = y0 + 5 + ro;
                const int sr = min(lr, NN - 1);
                GLOAD_LDS(base + ((2 << 18) | (sr << 9)) + ((f & 127) << 2),
                          smem + (lr & (RING - 1)) * SLOTF + 2 * NN + ((f & 127) << 2));
            }
        }

        // Counted wait: keep this iter's <=2 loads + prev 6 stores in flight,
        // but force the PREVIOUS iteration's stage loads (our window rows)
        // complete. Barrier makes that true across all 16 waves.
        asm volatile("s_waitcnt vmcnt(6)" ::: "memory");
        __builtin_amdgcn_s_barrier();
        asm volatile("" ::: "memory");

        const int y  = y0 + wrow;
        const int ri = (it << 2) + wrow;            // wave-uniform -> broadcast reads
        const float4 cu = *(const float4*)(smem + TBL + (ri << 3));
        const float4 cv = *(const float4*)(smem + TBL + (ri << 3) + 4);
        const float yr = (float)y;
        float* __restrict__ orow = ob + (size_t)y * NN;

#pragma unroll
        for (int k = 0; k < 2; ++k) {               // full unroll: all static
            const int xx = xb + (k << 8);
            const float4 sx = k ? sxB : sxA;
            const float du = sx.x * cu.x + sx.y * cu.y + sx.z * cu.z + sx.w * cu.w;
            const float dv = sx.x * cv.x + sx.y * cv.y + sx.z * cv.z + sx.w * cv.w;

            const float xn = fminf(fmaxf((float)xx - du, 0.0f), 511.0f);
            const float yn = fminf(fmaxf(yr - dv, 0.0f), 511.0f);
            // floor clamped to 510: at the exact-511 clamp edge the +1 tap gets
            // weight 1 and reproduces the edge value to 1 ulp.
            const int xf = min((int)floorf(xn), NN - 2);
            const int yf = min((int)floorf(yn), NN - 2);
            const float xv = xn - (float)xf;
            const float yv = yn - (float)yf;

            float o0, o1, o2;
            // In-ring: yf in [y0-1, y0+3] -> rows yf, yf+1 both resident.
            if ((unsigned)(yf - (y0 - 1)) <= 4u) {
                const float* t0 = smem + (yf & (RING - 1)) * SLOTF + xf;
                const float* t1 = smem + ((yf + 1) & (RING - 1)) * SLOTF + xf;
#pragma unroll
                for (int c = 0; c < NC; ++c) {
                    const float v00 = t0[c * NN];
                    const float v01 = t0[c * NN + 1];
                    const float v10 = t1[c * NN];
                    const float v11 = t1[c * NN + 1];
                    const float top = v00 + xv * (v01 - v00);
                    const float bot = v10 + xv * (v11 - v10);
                    const float r = top + yv * (bot - top);
                    if (c == 0) o0 = r; else if (c == 1) o1 = r; else o2 = r;
                }
            } else {
                // Large-displacement fallback (never taken for this data):
                // global bilinear gather. Extra vmcnt ops only make the
                // counted wait stricter -- still safe.
                const int xc = xf + 1, yc = yf + 1;
                const int o00 = yf * NN + xf, o01 = yf * NN + xc;
                const int o10 = yc * NN + xf, o11 = yc * NN + xc;
#pragma unroll
                for (int c = 0; c < NC; ++c) {
                    const float* img = base + c * NN * NN;
                    const float v00 = img[o00];
                    const float v01 = img[o01];
                    const float v10 = img[o10];
                    const float v11 = img[o11];
                    const float top = v00 + xv * (v01 - v00);
                    const float bot = v10 + xv * (v11 - v10);
                    const float r = top + yv * (bot - top);
                    if (c == 0) o0 = r; else if (c == 1) o1 = r; else o2 = r;
                }
            }

            // nontemporal: output never re-read; don't evict input from L2/L3.
            __builtin_nontemporal_store(o0, orow + 0 * NN * NN + xx);
            __builtin_nontemporal_store(o1, orow + 1 * NN * NN + xx);
            __builtin_nontemporal_store(o2, orow + 2 * NN * NN + xx);
        }
    }
}

extern "C" void kernel_launch(void* const* d_in, const int* in_sizes, int n_in,
                              void* d_out, int out_size, void* d_ws, size_t ws_size,
                              hipStream_t stream) {
    const float* x  = (const float*)d_in[0];
    const float* Fx = (const float*)d_in[1];
    const float* Fy = (const float*)d_in[2];
    float* out = (float*)d_out;
    float* ws  = (float*)d_ws;   // 8 KB sine table (re-built every call; ws re-poisoned)

    // typ = n * sqrt(pi*log(cut)) / 2 ; scale = sqrt(T/typ^2) * n
    const double typ = 512.0 * sqrt(M_PI * log(4.0)) / 2.0;
    const float scale = (float)(sqrt(0.01 / (typ * typ)) * 512.0);

    sine_table_kernel<<<8, 256, 0, stream>>>(ws);
    // 256 blocks = 64 images x 4 strips of 128 rows; 1 block per CU.
    diffeo_kernel<<<256, 1024, 0, stream>>>(x, Fx, Fy, out, ws, scale);
}